// Round 1
// baseline (115.878 us; speedup 1.0000x reference)
//
#include <hip/hip_runtime.h>

typedef __attribute__((ext_vector_type(8))) short bf16x8;
typedef __attribute__((ext_vector_type(4))) float f32x4;

__device__ __forceinline__ unsigned short f2bf(float f) {
    union { float f; unsigned int u; } v; v.f = f;
    unsigned int r = v.u + 0x7fffu + ((v.u >> 16) & 1u);   // RNE
    return (unsigned short)(r >> 16);
}
__device__ __forceinline__ float bf2f(unsigned short h) {
    union { unsigned int u; float f; } v; v.u = ((unsigned int)h) << 16;
    return v.f;
}

// Pack W1 (128x256) and W2 (256x128) f32 -> bf16 B-fragment order in ws.
// Frag element (lane l, j) = W[kk*32 + (l>>4)*8 + j][nn*16 + (l&15)].
// W1: frag f = kk*16+nn (kk<4, nn<16) at ws[f*512 ...]; W2 at ws+32768, f = kk*8+nn (kk<8, nn<8).
__global__ void prep_weights(const float* __restrict__ W1, const float* __restrict__ W2,
                             unsigned short* __restrict__ wbuf) {
    int t = blockIdx.x * 256 + threadIdx.x;   // [0, 65536)
    int j = t & 7, l = (t >> 3) & 63, f = (t >> 9) & 63;
    float v;
    if (t < 32768) {
        int kk = f >> 4, nn = f & 15;
        int k = kk * 32 + ((l >> 4) << 3) + j;
        int n = nn * 16 + (l & 15);
        v = W1[k * 256 + n];
    } else {
        int kk = f >> 3, nn = f & 7;
        int k = kk * 32 + ((l >> 4) << 3) + j;
        int n = nn * 16 + (l & 15);
        v = W2[k * 128 + n];
    }
    wbuf[t] = f2bf(v);
}

__global__ __launch_bounds__(256, 2)
void coupling_main(const float* __restrict__ x, const unsigned short* __restrict__ wbuf,
                   const float* __restrict__ b1, const float* __restrict__ b2,
                   float* __restrict__ out) {
    __shared__ unsigned short sFirst[64 * 128];   // 16KB, XOR-swizzled 16B slots
    __shared__ unsigned short sSecond[64 * 128];  // 16KB, same swizzle
    __shared__ unsigned short sH[64 * 256];       // 32KB, XOR-swizzled

    const int tid = threadIdx.x;
    const int lane = tid & 63;
    const int w = tid >> 6;          // wave 0..3
    const int l15 = lane & 15;
    const int grp = lane >> 4;
    const int row0 = blockIdx.x * 64;

    // ---- wave's W1 slice into registers (cols 64w..64w+63) ----
    bf16x8 w1f[4][4];
#pragma unroll
    for (int kk = 0; kk < 4; ++kk)
#pragma unroll
      for (int ni = 0; ni < 4; ++ni) {
        int f = kk * 16 + (4 * w + ni);
        w1f[kk][ni] = *reinterpret_cast<const bf16x8*>(wbuf + (f * 64 + lane) * 8);
      }
    float b1v[4];
#pragma unroll
    for (int ni = 0; ni < 4; ++ni) b1v[ni] = b1[w * 64 + ni * 16 + l15];

    // ---- stage x tile: first->bf16 (swz), second->bf16 (swz) ----
    const float4* xt = reinterpret_cast<const float4*>(x + (size_t)row0 * 256);
#pragma unroll
    for (int i = 0; i < 16; ++i) {
        int f4 = i * 256 + tid;           // [0,4096)
        float4 v = xt[f4];
        int row = f4 >> 6, c4 = f4 & 63;  // covers x cols 4c4..4c4+3
        unsigned int fp = (unsigned int)f2bf(v.x) | ((unsigned int)f2bf(v.z) << 16);
        unsigned int sp = (unsigned int)f2bf(v.y) | ((unsigned int)f2bf(v.w) << 16);
        int slot = (c4 >> 2) ^ (row & 15);
        reinterpret_cast<unsigned int*>(sFirst)[row * 64 + slot * 4 + (c4 & 3)] = fp;
        reinterpret_cast<unsigned int*>(sSecond)[row * 64 + slot * 4 + (c4 & 3)] = sp;
    }
    __syncthreads();

    // ---- phase 2: h = relu(first @ W1 + b1), wave owns h cols 64w..64w+63 ----
    f32x4 hacc[4][4];
#pragma unroll
    for (int mi = 0; mi < 4; ++mi)
#pragma unroll
      for (int ni = 0; ni < 4; ++ni)
        hacc[mi][ni] = (f32x4){0.f, 0.f, 0.f, 0.f};

#pragma unroll
    for (int mi = 0; mi < 4; ++mi) {
        int row = mi * 16 + l15;
        bf16x8 a[4];
#pragma unroll
        for (int kk = 0; kk < 4; ++kk) {
            int slot = (kk * 4 + grp) ^ (row & 15);
            a[kk] = *reinterpret_cast<const bf16x8*>(sFirst + row * 128 + slot * 8);
        }
#pragma unroll
        for (int kk = 0; kk < 4; ++kk)
#pragma unroll
          for (int ni = 0; ni < 4; ++ni)
            hacc[mi][ni] = __builtin_amdgcn_mfma_f32_16x16x32_bf16(a[kk], w1f[kk][ni], hacc[mi][ni], 0, 0, 0);
    }

    // ---- issue W2 slice loads early (overlap with h-store) ----
    bf16x8 w2f[8][2];
#pragma unroll
    for (int kk = 0; kk < 8; ++kk)
#pragma unroll
      for (int ni = 0; ni < 2; ++ni) {
        int f = kk * 8 + (2 * w + ni);
        w2f[kk][ni] = *reinterpret_cast<const bf16x8*>(wbuf + 32768 + (f * 64 + lane) * 8);
      }
    float b2v[2];
#pragma unroll
    for (int ni = 0; ni < 2; ++ni) b2v[ni] = b2[w * 32 + ni * 16 + l15];

    // ---- h (relu+bias) -> sH via verified C-layout: row=(l>>4)*4+r, col=l&15 ----
#pragma unroll
    for (int mi = 0; mi < 4; ++mi)
#pragma unroll
      for (int ni = 0; ni < 4; ++ni) {
        int col = w * 64 + ni * 16 + l15;
#pragma unroll
        for (int r = 0; r < 4; ++r) {
            int row = mi * 16 + grp * 4 + r;
            float hv = hacc[mi][ni][r] + b1v[ni];
            hv = fmaxf(hv, 0.f);
            int slot = (col >> 3) ^ (row & 15);
            sH[row * 256 + slot * 8 + (col & 7)] = f2bf(hv);
        }
      }
    __syncthreads();

    // ---- phase 3: m = h @ W2 + b2, wave owns m cols 32w..32w+31 ----
    f32x4 macc[4][2];
#pragma unroll
    for (int mi = 0; mi < 4; ++mi)
#pragma unroll
      for (int ni = 0; ni < 2; ++ni)
        macc[mi][ni] = (f32x4){0.f, 0.f, 0.f, 0.f};

#pragma unroll
    for (int mi = 0; mi < 4; ++mi) {
        int row = mi * 16 + l15;
        bf16x8 a[8];
#pragma unroll
        for (int kk = 0; kk < 8; ++kk) {
            int slot = (kk * 4 + grp) ^ (row & 15);
            a[kk] = *reinterpret_cast<const bf16x8*>(sH + row * 256 + slot * 8);
        }
#pragma unroll
        for (int kk = 0; kk < 8; ++kk)
#pragma unroll
          for (int ni = 0; ni < 2; ++ni)
            macc[mi][ni] = __builtin_amdgcn_mfma_f32_16x16x32_bf16(a[kk], w2f[kk][ni], macc[mi][ni], 0, 0, 0);
    }

    // ---- epilogue: out[row][2c]=first[c], out[row][2c+1]=second[c]+m[c] ----
    // direct from C-layout: quarter-wave writes one aligned 128B segment
#pragma unroll
    for (int mi = 0; mi < 4; ++mi)
#pragma unroll
      for (int ni = 0; ni < 2; ++ni) {
        int col = w * 32 + ni * 16 + l15;   // [0,128)
#pragma unroll
        for (int r = 0; r < 4; ++r) {
            int row = mi * 16 + grp * 4 + r;
            int slotF = (col >> 3) ^ (row & 15);
            float fv = bf2f(sFirst[row * 128 + slotF * 8 + (col & 7)]);
            float sv = bf2f(sSecond[row * 128 + slotF * 8 + (col & 7)]);
            float mv = macc[mi][ni][r] + b2v[ni];
            float2 o = make_float2(fv, sv + mv);
            *reinterpret_cast<float2*>(out + (size_t)(row0 + row) * 256 + col * 2) = o;
        }
      }
}

extern "C" void kernel_launch(void* const* d_in, const int* in_sizes, int n_in,
                              void* d_out, int out_size, void* d_ws, size_t ws_size,
                              hipStream_t stream) {
    const float* x  = (const float*)d_in[0];
    const float* W1 = (const float*)d_in[1];
    const float* b1 = (const float*)d_in[2];
    const float* W2 = (const float*)d_in[3];
    const float* b2 = (const float*)d_in[4];
    float* out = (float*)d_out;
    unsigned short* wbuf = (unsigned short*)d_ws;   // 128 KB

    int Brows = in_sizes[0] / 256;
    prep_weights<<<256, 256, 0, stream>>>(W1, W2, wbuf);
    coupling_main<<<Brows / 64, 256, 0, stream>>>(x, wbuf, b1, b2, out);
}